// Round 1
// baseline (53.168 us; speedup 1.0000x reference)
//
#include <hip/hip_runtime.h>
#include <hip/hip_bf16.h>

#define NB 32
#define NQ 1024
#define NK 1024
#define ND 64
#define BQ 64      // q rows per block (4 waves x 16)
#define BK 64      // keys per tile
#define LSTR 72    // LDS row stride in bf16 elems: 144B = 9*16B (b128-aligned, banks spread)

typedef __attribute__((ext_vector_type(8))) __bf16 bf16x8;
typedef __attribute__((ext_vector_type(8))) short  s16x8;
typedef __attribute__((ext_vector_type(4))) short  s16x4;
typedef __attribute__((ext_vector_type(4))) float  f32x4;

// f32 -> bf16 round-to-nearest-even
static __device__ __forceinline__ short f2bf(float f) {
  unsigned u = __builtin_bit_cast(unsigned, f);
  u += 0x7fffu + ((u >> 16) & 1u);
  return (short)(u >> 16);
}

__launch_bounds__(256, 2)
__global__ void attn_fwd(const float* __restrict__ Qp,
                         const float* __restrict__ Kp,
                         const float* __restrict__ Vp,
                         const int* __restrict__ VLp,
                         float* __restrict__ Op) {
  __shared__ __align__(16) short Kt[BK * LSTR];        // [key][d] bf16
  __shared__ __align__(16) short Vt[ND * LSTR];        // [d][key] bf16 (transposed)
  __shared__ __align__(16) short Pt[4][16 * LSTR];     // per-wave P tile [qrow][key]

  const int wg  = blockIdx.x;
  const int swz = (wg & 7) * 64 + (wg >> 3);   // bijective XCD swizzle (512 = 8*64)
  const int b   = swz >> 4;
  const int qb  = swz & 15;

  const int tid  = threadIdx.x;
  const int wid  = tid >> 6;
  const int lane = tid & 63;
  const int l16  = lane & 15;
  const int grp  = lane >> 4;

  // valid_lens dtype detection: lens are in [1,1024] (never 0). If the buffer
  // is int64 (little-endian), word 1 is the high word of element 0 == 0.
  const bool is64 = (VLp[1] == 0);
  const int  len  = is64 ? VLp[2 * b] : VLp[b];

  // fold 1/sqrt(64) and log2(e) into Q so softmax uses exp2 directly
  const float qscale = 0.125f * 1.44269504088896341f;

  // ---- Q fragments (A-layout: row = l16, k = ks*32 + grp*8 + j) ----
  bf16x8 qf[2];
  {
    const int qrow = qb * BQ + wid * 16 + l16;
    const float* qsrc = Qp + ((size_t)b * NQ + qrow) * ND + grp * 8;
#pragma unroll
    for (int ks = 0; ks < 2; ++ks) {
      float4 a = *(const float4*)(qsrc + ks * 32);
      float4 c = *(const float4*)(qsrc + ks * 32 + 4);
      s16x8 t;
      t[0] = f2bf(a.x * qscale); t[1] = f2bf(a.y * qscale);
      t[2] = f2bf(a.z * qscale); t[3] = f2bf(a.w * qscale);
      t[4] = f2bf(c.x * qscale); t[5] = f2bf(c.y * qscale);
      t[6] = f2bf(c.z * qscale); t[7] = f2bf(c.w * qscale);
      qf[ks] = __builtin_bit_cast(bf16x8, t);
    }
  }

  const f32x4 vzero = {0.f, 0.f, 0.f, 0.f};
  f32x4 oacc[4];
#pragma unroll
  for (int i = 0; i < 4; ++i) oacc[i] = vzero;
  float mrun[4] = {-__builtin_inff(), -__builtin_inff(),
                   -__builtin_inff(), -__builtin_inff()};
  float lrun[4] = {0.f, 0.f, 0.f, 0.f};

  // tiles with kt*BK >= len contribute exactly zero probability -> skip
  const int ntiles = (len + BK - 1) >> 6;

  const float* kbase = Kp + (size_t)b * NK * ND;
  const float* vbase = Vp + (size_t)b * NK * ND;

  for (int kt = 0; kt < ntiles; ++kt) {
    // ---- stage K tile, coalesced flat reads ----
    {
      const float* ks_ = kbase + kt * BK * ND;
#pragma unroll
      for (int it = 0; it < 4; ++it) {
        int e = it * 1024 + tid * 4;
        int key = e >> 6, d0 = e & 63;
        float4 kv = *(const float4*)(ks_ + e);
        s16x4 kb = { f2bf(kv.x), f2bf(kv.y), f2bf(kv.z), f2bf(kv.w) };
        *(s16x4*)&Kt[key * LSTR + d0] = kb;
      }
      // ---- stage V tile transposed: thread = one key, 16 d values ----
      const int vkey = tid & 63;
      const int vd0  = (tid >> 6) * 16;
      const float* vs_ = vbase + ((size_t)kt * BK + vkey) * ND + vd0;
#pragma unroll
      for (int it = 0; it < 4; ++it) {
        float4 vv = *(const float4*)(vs_ + it * 4);
        Vt[(vd0 + it * 4 + 0) * LSTR + vkey] = f2bf(vv.x);
        Vt[(vd0 + it * 4 + 1) * LSTR + vkey] = f2bf(vv.y);
        Vt[(vd0 + it * 4 + 2) * LSTR + vkey] = f2bf(vv.z);
        Vt[(vd0 + it * 4 + 3) * LSTR + vkey] = f2bf(vv.w);
      }
    }
    __syncthreads();

    // ---- S = Q K^T (per wave: 16 rows x 64 keys) ----
    f32x4 sc[4];
#pragma unroll
    for (int n = 0; n < 4; ++n) {
      f32x4 acc = vzero;
#pragma unroll
      for (int ks = 0; ks < 2; ++ks) {
        bf16x8 kf = __builtin_bit_cast(bf16x8,
            *(const s16x8*)&Kt[(n * 16 + l16) * LSTR + ks * 32 + grp * 8]);
        acc = __builtin_amdgcn_mfma_f32_16x16x32_bf16(qf[ks], kf, acc, 0, 0, 0);
      }
      sc[n] = acc;
    }

    // ---- mask + online softmax (log2 domain) ----
    // C/D layout: col(key) = l16, row(q) = grp*4 + r
    float tmax[4] = {-1e30f, -1e30f, -1e30f, -1e30f};
#pragma unroll
    for (int n = 0; n < 4; ++n) {
      int keyg = kt * BK + n * 16 + l16;
      bool ok = keyg < len;
#pragma unroll
      for (int r = 0; r < 4; ++r) {
        float v = ok ? sc[n][r] : -1.0e6f;
        sc[n][r] = v;
        tmax[r] = fmaxf(tmax[r], v);
      }
    }
#pragma unroll
    for (int r = 0; r < 4; ++r) {
#pragma unroll
      for (int off = 1; off < 16; off <<= 1)
        tmax[r] = fmaxf(tmax[r], __shfl_xor(tmax[r], off));
    }
    float alpha[4];
#pragma unroll
    for (int r = 0; r < 4; ++r) {
      float mn = fmaxf(mrun[r], tmax[r]);
      alpha[r] = exp2f(mrun[r] - mn);
      mrun[r] = mn;
    }
    float p[4][4];
    float rs[4] = {0.f, 0.f, 0.f, 0.f};
#pragma unroll
    for (int n = 0; n < 4; ++n)
#pragma unroll
      for (int r = 0; r < 4; ++r) {
        float pv = exp2f(sc[n][r] - mrun[r]);
        p[n][r] = pv;
        rs[r] += pv;
      }
#pragma unroll
    for (int r = 0; r < 4; ++r) {
#pragma unroll
      for (int off = 1; off < 16; off <<= 1)
        rs[r] += __shfl_xor(rs[r], off);
      lrun[r] = lrun[r] * alpha[r] + rs[r];
    }
#pragma unroll
    for (int nd = 0; nd < 4; ++nd)
#pragma unroll
      for (int r = 0; r < 4; ++r)
        oacc[nd][r] *= alpha[r];

    // ---- P: C-layout -> bf16 A-layout via per-wave LDS tile ----
    short* pw = Pt[wid];
#pragma unroll
    for (int n = 0; n < 4; ++n)
#pragma unroll
      for (int r = 0; r < 4; ++r)
        pw[(grp * 4 + r) * LSTR + n * 16 + l16] = f2bf(p[n][r]);

    __syncthreads();  // orders P RAW; also cheap insurance before PV reads

    bf16x8 pf[2];
#pragma unroll
    for (int ks = 0; ks < 2; ++ks)
      pf[ks] = __builtin_bit_cast(bf16x8,
          *(const s16x8*)&pw[l16 * LSTR + ks * 32 + grp * 8]);

    // ---- O += P V ----
#pragma unroll
    for (int nd = 0; nd < 4; ++nd) {
#pragma unroll
      for (int ks = 0; ks < 2; ++ks) {
        bf16x8 vf = __builtin_bit_cast(bf16x8,
            *(const s16x8*)&Vt[(nd * 16 + l16) * LSTR + ks * 32 + grp * 8]);
        oacc[nd] = __builtin_amdgcn_mfma_f32_16x16x32_bf16(pf[ks], vf, oacc[nd], 0, 0, 0);
      }
    }
    __syncthreads();  // protect Kt/Vt before next tile's staging
  }

  // ---- epilogue: normalize and store ----
  float inv[4];
#pragma unroll
  for (int r = 0; r < 4; ++r) inv[r] = 1.0f / lrun[r];
  float* obase = Op + ((size_t)b * NQ + qb * BQ + wid * 16) * ND;
#pragma unroll
  for (int nd = 0; nd < 4; ++nd)
#pragma unroll
    for (int r = 0; r < 4; ++r)
      obase[(grp * 4 + r) * ND + nd * 16 + l16] = oacc[nd][r] * inv[r];
}

extern "C" void kernel_launch(void* const* d_in, const int* in_sizes, int n_in,
                              void* d_out, int out_size, void* d_ws, size_t ws_size,
                              hipStream_t stream) {
  const float* Qp = (const float*)d_in[0];
  const float* Kp = (const float*)d_in[1];
  const float* Vp = (const float*)d_in[2];
  const int*   VL = (const int*)d_in[3];
  float* Op = (float*)d_out;
  attn_fwd<<<dim3(NB * (NQ / BQ)), dim3(256), 0, stream>>>(Qp, Kp, Vp, VL, Op);
}

// Round 2
// 46.518 us; speedup vs baseline: 1.1429x; 1.1429x over previous
//
#include <hip/hip_runtime.h>
#include <hip/hip_bf16.h>

#define NB 32
#define NQ 1024
#define NK 1024
#define ND 64
#define BQ 64      // q rows per block (4 row-groups x 16, each owned by a wave PAIR)
#define BK 64      // keys per tile
#define LSTR 72    // LDS row stride in bf16 elems: 144B = 9*16B (b128-aligned, 2-way max)
#define TSZ (BK * LSTR)   // shorts per K/V tile

typedef __attribute__((ext_vector_type(8))) __bf16 bf16x8;
typedef __attribute__((ext_vector_type(8))) short  s16x8;
typedef __attribute__((ext_vector_type(4))) short  s16x4;
typedef __attribute__((ext_vector_type(4))) float  f32x4;

// f32 -> bf16 round-to-nearest-even
static __device__ __forceinline__ short f2bf(float f) {
  unsigned u = __builtin_bit_cast(unsigned, f);
  u += 0x7fffu + ((u >> 16) & 1u);
  return (short)(u >> 16);
}

__launch_bounds__(512, 4)
__global__ void attn_fwd(const float* __restrict__ Qp,
                         const float* __restrict__ Kp,
                         const float* __restrict__ Vp,
                         const int* __restrict__ VLp,
                         float* __restrict__ Op) {
  // [ Kt: 2 tiles ][ Vt: 2 tiles ][ Pt: 8 waves x 16 x LSTR ]  = 55296 B
  __shared__ __align__(16) short SM[4 * TSZ + 8 * 16 * LSTR];
  short* Kt = SM;             // [2][key][d]   bf16
  short* Vt = SM + 2 * TSZ;   // [2][d][key]   bf16 (transposed)
  short* Pt = SM + 4 * TSZ;   // [8][qrow][key]

  const int wg = blockIdx.x;          // natural order: round-robin XCDs, balanced
  const int b  = wg >> 4;
  const int qb = wg & 15;

  const int tid  = threadIdx.x;
  const int wid  = tid >> 6;          // 0..7
  const int lane = tid & 63;
  const int l16  = lane & 15;
  const int grp  = lane >> 4;
  const int qgrp = wid >> 1;          // which 16 q-rows this wave pair owns
  const int par  = wid & 1;           // k-tile parity this wave handles

  // valid_lens dtype detection (lens in [1,1024], never 0): int64 => word1==0
  const bool is64 = (VLp[1] == 0);
  const int  len  = is64 ? VLp[2 * b] : VLp[b];

  const float qscale = 0.125f * 1.44269504088896341f;  // 1/sqrt(64) * log2(e)

  // ---- Q fragments (A-layout: row = l16, k = ks*32 + grp*8 + j) ----
  bf16x8 qf[2];
  {
    const int qrow = qb * BQ + qgrp * 16 + l16;
    const float* qsrc = Qp + ((size_t)b * NQ + qrow) * ND + grp * 8;
#pragma unroll
    for (int ks = 0; ks < 2; ++ks) {
      float4 a = *(const float4*)(qsrc + ks * 32);
      float4 c = *(const float4*)(qsrc + ks * 32 + 4);
      s16x8 t;
      t[0] = f2bf(a.x * qscale); t[1] = f2bf(a.y * qscale);
      t[2] = f2bf(a.z * qscale); t[3] = f2bf(a.w * qscale);
      t[4] = f2bf(c.x * qscale); t[5] = f2bf(c.y * qscale);
      t[6] = f2bf(c.z * qscale); t[7] = f2bf(c.w * qscale);
      qf[ks] = __builtin_bit_cast(bf16x8, t);
    }
  }

  const f32x4 vzero = {0.f, 0.f, 0.f, 0.f};
  f32x4 oacc[4];
#pragma unroll
  for (int i = 0; i < 4; ++i) oacc[i] = vzero;
  float mrun[4] = {-1e30f, -1e30f, -1e30f, -1e30f};
  float lrun[4] = {0.f, 0.f, 0.f, 0.f};

  const int ntiles = (len + BK - 1) >> 6;   // tiles fully past len contribute 0
  const int nsup   = (ntiles + 1) >> 1;     // super-iterations (2 tiles each)

  const float* kbase = Kp + (size_t)b * NK * ND;
  const float* vbase = Vp + (size_t)b * NK * ND;

  for (int it = 0; it < nsup; ++it) {
    const int t0 = 2 * it;

    // ---- stage up to 2 K tiles (contiguous 2-tile span), 512 threads ----
    {
      const float* ks_ = kbase + (size_t)t0 * BK * ND;
#pragma unroll
      for (int i = 0; i < 4; ++i) {
        if (t0 + (i >> 1) < ntiles) {            // uniform per i
          int e = i * 2048 + tid * 4;            // elem in [0, 8192)
          int tl = e >> 12, key = (e >> 6) & 63, d0 = e & 63;
          float4 kv = *(const float4*)(ks_ + e);
          s16x4 kb = { f2bf(kv.x), f2bf(kv.y), f2bf(kv.z), f2bf(kv.w) };
          *(s16x4*)&Kt[tl * TSZ + key * LSTR + d0] = kb;
        }
      }
      // ---- stage 2 V tiles transposed: waves 0-3 -> tile0, 4-7 -> tile1 ----
      const int vt  = tid >> 8;                  // wave-uniform
      const int vkey = tid & 63;
      const int vd0  = ((tid >> 6) & 3) * 16;
      if (t0 + vt < ntiles) {
        const float* vs_ = vbase + ((size_t)(t0 + vt) * BK + vkey) * ND + vd0;
#pragma unroll
        for (int i = 0; i < 4; ++i) {
          float4 vv = *(const float4*)(vs_ + i * 4);
          Vt[vt * TSZ + (vd0 + i * 4 + 0) * LSTR + vkey] = f2bf(vv.x);
          Vt[vt * TSZ + (vd0 + i * 4 + 1) * LSTR + vkey] = f2bf(vv.y);
          Vt[vt * TSZ + (vd0 + i * 4 + 2) * LSTR + vkey] = f2bf(vv.z);
          Vt[vt * TSZ + (vd0 + i * 4 + 3) * LSTR + vkey] = f2bf(vv.w);
        }
      }
    }
    __syncthreads();

    const int myt = t0 + par;
    if (myt < ntiles) {                          // wave-uniform branch
      const short* kw = &Kt[par * TSZ];
      const short* vw = &Vt[par * TSZ];

      // ---- S = Q K^T (16 rows x 64 keys) ----
      f32x4 sc[4];
#pragma unroll
      for (int n = 0; n < 4; ++n) {
        f32x4 acc = vzero;
#pragma unroll
        for (int ks = 0; ks < 2; ++ks) {
          bf16x8 kf = __builtin_bit_cast(bf16x8,
              *(const s16x8*)&kw[(n * 16 + l16) * LSTR + ks * 32 + grp * 8]);
          acc = __builtin_amdgcn_mfma_f32_16x16x32_bf16(qf[ks], kf, acc, 0, 0, 0);
        }
        sc[n] = acc;
      }

      // ---- mask + online softmax (log2 domain) ----
      float tmax[4] = {-1e30f, -1e30f, -1e30f, -1e30f};
#pragma unroll
      for (int n = 0; n < 4; ++n) {
        int keyg = myt * BK + n * 16 + l16;
        bool ok = keyg < len;
#pragma unroll
        for (int r = 0; r < 4; ++r) {
          float v = ok ? sc[n][r] : -1.0e6f;
          sc[n][r] = v;
          tmax[r] = fmaxf(tmax[r], v);
        }
      }
#pragma unroll
      for (int r = 0; r < 4; ++r) {
#pragma unroll
        for (int off = 1; off < 16; off <<= 1)
          tmax[r] = fmaxf(tmax[r], __shfl_xor(tmax[r], off));
      }
      float alpha[4];
#pragma unroll
      for (int r = 0; r < 4; ++r) {
        float mn = fmaxf(mrun[r], tmax[r]);
        alpha[r] = exp2f(mrun[r] - mn);
        mrun[r] = mn;
      }
      float p[4][4];
      float rs[4] = {0.f, 0.f, 0.f, 0.f};
#pragma unroll
      for (int n = 0; n < 4; ++n)
#pragma unroll
        for (int r = 0; r < 4; ++r) {
          float pv = exp2f(sc[n][r] - mrun[r]);
          p[n][r] = pv;
          rs[r] += pv;
        }
#pragma unroll
      for (int r = 0; r < 4; ++r) {
#pragma unroll
        for (int off = 1; off < 16; off <<= 1)
          rs[r] += __shfl_xor(rs[r], off);
        lrun[r] = lrun[r] * alpha[r] + rs[r];
      }
#pragma unroll
      for (int nd = 0; nd < 4; ++nd)
#pragma unroll
        for (int r = 0; r < 4; ++r)
          oacc[nd][r] *= alpha[r];

      // ---- P: C-layout -> bf16 A-layout, wave-local LDS round-trip ----
      short* pw = &Pt[wid * 16 * LSTR];
#pragma unroll
      for (int n = 0; n < 4; ++n)
#pragma unroll
        for (int r = 0; r < 4; ++r)
          pw[(grp * 4 + r) * LSTR + n * 16 + l16] = f2bf(p[n][r]);

      // wave-local RAW: drain this wave's LDS ops; fence scheduler (rule #18)
      asm volatile("s_waitcnt lgkmcnt(0)" ::: "memory");
      __builtin_amdgcn_sched_barrier(0);

      bf16x8 pf[2];
#pragma unroll
      for (int ks = 0; ks < 2; ++ks)
        pf[ks] = __builtin_bit_cast(bf16x8,
            *(const s16x8*)&pw[l16 * LSTR + ks * 32 + grp * 8]);

      // ---- O += P V ----
#pragma unroll
      for (int nd = 0; nd < 4; ++nd) {
#pragma unroll
        for (int ks = 0; ks < 2; ++ks) {
          bf16x8 vf = __builtin_bit_cast(bf16x8,
              *(const s16x8*)&vw[(nd * 16 + l16) * LSTR + ks * 32 + grp * 8]);
          oacc[nd] = __builtin_amdgcn_mfma_f32_16x16x32_bf16(pf[ks], vf, oacc[nd], 0, 0, 0);
        }
      }
    }
    __syncthreads();   // protect Kt/Vt before next staging (and CB reuse after loop)
  }

  // ---- combine wave pairs: odd wave publishes (O, m, l) via LDS ----
  float* CB = (float*)SM;   // 256 rows x 24 f32 = 24576 B, overlays Kt/Vt
  const int crow = qgrp * 64 + lane;
  if (par == 1) {
    float* dst = CB + (size_t)crow * 24;
#pragma unroll
    for (int nd = 0; nd < 4; ++nd) *(f32x4*)(dst + nd * 4) = oacc[nd];
    f32x4 mv = {mrun[0], mrun[1], mrun[2], mrun[3]};
    f32x4 lv = {lrun[0], lrun[1], lrun[2], lrun[3]};
    *(f32x4*)(dst + 16) = mv;
    *(f32x4*)(dst + 20) = lv;
  }
  __syncthreads();
  if (par == 0) {
    const float* src = CB + (size_t)crow * 24;
    f32x4 oo[4];
#pragma unroll
    for (int nd = 0; nd < 4; ++nd) oo[nd] = *(const f32x4*)(src + nd * 4);
    f32x4 mo = *(const f32x4*)(src + 16);
    f32x4 lo = *(const f32x4*)(src + 20);

    float ae[4], ao[4], inv[4];
#pragma unroll
    for (int r = 0; r < 4; ++r) {
      float m = fmaxf(mrun[r], mo[r]);
      ae[r] = exp2f(mrun[r] - m);
      ao[r] = exp2f(mo[r] - m);
      float l = lrun[r] * ae[r] + lo[r] * ao[r];
      inv[r] = 1.0f / l;
    }
    float* obase = Op + ((size_t)b * NQ + qb * BQ + qgrp * 16) * ND;
#pragma unroll
    for (int nd = 0; nd < 4; ++nd)
#pragma unroll
      for (int r = 0; r < 4; ++r)
        obase[(grp * 4 + r) * ND + nd * 16 + l16] =
            (oacc[nd][r] * ae[r] + oo[nd][r] * ao[r]) * inv[r];
  }
}

extern "C" void kernel_launch(void* const* d_in, const int* in_sizes, int n_in,
                              void* d_out, int out_size, void* d_ws, size_t ws_size,
                              hipStream_t stream) {
  const float* Qp = (const float*)d_in[0];
  const float* Kp = (const float*)d_in[1];
  const float* Vp = (const float*)d_in[2];
  const int*   VL = (const int*)d_in[3];
  float* Op = (float*)d_out;
  attn_fwd<<<dim3(NB * (NQ / BQ)), dim3(512), 0, stream>>>(Qp, Kp, Vp, VL, Op);
}

// Round 3
// 44.109 us; speedup vs baseline: 1.2054x; 1.0546x over previous
//
#include <hip/hip_runtime.h>
#include <hip/hip_bf16.h>

#define NB 32
#define NQ 1024
#define NK 1024
#define ND 64
#define BQ 64      // q rows per block (4 row-groups x 16, each owned by a wave PAIR)
#define BK 64      // keys per tile
#define LSTR 72    // LDS row stride in bf16 elems: 144B = 9*16B (b128-aligned, 2-way max)
#define TSZ (BK * LSTR)   // shorts per K/V tile

typedef __attribute__((ext_vector_type(8))) __bf16 bf16x8;
typedef __attribute__((ext_vector_type(8))) short  s16x8;
typedef __attribute__((ext_vector_type(4))) short  s16x4;
typedef __attribute__((ext_vector_type(4))) float  f32x4;

// f32 -> bf16 round-to-nearest-even
static __device__ __forceinline__ short f2bf(float f) {
  unsigned u = __builtin_bit_cast(unsigned, f);
  u += 0x7fffu + ((u >> 16) & 1u);
  return (short)(u >> 16);
}

__launch_bounds__(512, 4)
__global__ void attn_fwd(const float* __restrict__ Qp,
                         const float* __restrict__ Kp,
                         const float* __restrict__ Vp,
                         const int* __restrict__ VLp,
                         float* __restrict__ Op) {
  // [ Kt: 2 tiles ][ Vt: 2 tiles ][ Pt: 8 waves x 16 x LSTR ]  = 55296 B
  __shared__ __align__(16) short SM[4 * TSZ + 8 * 16 * LSTR];
  short* Kt = SM;             // [2][key][d]   bf16
  short* Vt = SM + 2 * TSZ;   // [2][d][key]   bf16 (transposed)
  short* Pt = SM + 4 * TSZ;   // [8][qrow][key]

  const int wg  = blockIdx.x;
  const int swz = (wg & 7) * 64 + (wg >> 3);   // bijective XCD swizzle (512 = 8*64)
  const int b   = swz >> 4;                    // 4 batches per XCD -> K/V L2-resident
  const int qb  = swz & 15;

  const int tid  = threadIdx.x;
  const int wid  = tid >> 6;          // 0..7
  const int lane = tid & 63;
  const int l16  = lane & 15;
  const int grp  = lane >> 4;
  const int qgrp = wid >> 1;          // which 16 q-rows this wave pair owns
  const int par  = wid & 1;           // k-tile parity this wave handles

  // valid_lens dtype detection (lens in [1,1024], never 0): int64 => word1==0
  const bool is64 = (VLp[1] == 0);
  const int  len  = is64 ? VLp[2 * b] : VLp[b];

  const float qscale = 0.125f * 1.44269504088896341f;  // 1/sqrt(64) * log2(e)

  // ---- Q fragments (A-layout: row = l16, k = ks*32 + grp*8 + j) ----
  bf16x8 qf[2];
  {
    const int qrow = qb * BQ + qgrp * 16 + l16;
    const float* qsrc = Qp + ((size_t)b * NQ + qrow) * ND + grp * 8;
#pragma unroll
    for (int ks = 0; ks < 2; ++ks) {
      float4 a = *(const float4*)(qsrc + ks * 32);
      float4 c = *(const float4*)(qsrc + ks * 32 + 4);
      s16x8 t;
      t[0] = f2bf(a.x * qscale); t[1] = f2bf(a.y * qscale);
      t[2] = f2bf(a.z * qscale); t[3] = f2bf(a.w * qscale);
      t[4] = f2bf(c.x * qscale); t[5] = f2bf(c.y * qscale);
      t[6] = f2bf(c.z * qscale); t[7] = f2bf(c.w * qscale);
      qf[ks] = __builtin_bit_cast(bf16x8, t);
    }
  }

  const f32x4 vzero = {0.f, 0.f, 0.f, 0.f};
  f32x4 oacc[4];
#pragma unroll
  for (int i = 0; i < 4; ++i) oacc[i] = vzero;
  float mrun[4] = {-1e30f, -1e30f, -1e30f, -1e30f};
  float lrun[4] = {0.f, 0.f, 0.f, 0.f};

  const int ntiles = (len + BK - 1) >> 6;   // tiles fully past len contribute 0
  const int nsup   = (ntiles + 1) >> 1;     // super-iterations (2 tiles each)

  const float* kbase = Kp + (size_t)b * NK * ND;
  const float* vbase = Vp + (size_t)b * NK * ND;

  // V staging role (constant per thread)
  const int vt   = tid >> 8;                // waves 0-3 -> tile0, 4-7 -> tile1
  const int vkey = tid & 63;
  const int vd0  = ((tid >> 6) & 3) * 16;

  // ---- T14 async staging: issue loads early into regs, commit to LDS late ----
  float4 kreg[4], vreg[4];
  auto stage_issue = [&](int t0) {
    const float* ks_ = kbase + (size_t)t0 * BK * ND;
#pragma unroll
    for (int i = 0; i < 4; ++i)
      kreg[i] = *(const float4*)(ks_ + i * 2048 + tid * 4);
    const float* vs_ = vbase + ((size_t)(t0 + vt) * BK + vkey) * ND + vd0;
#pragma unroll
    for (int i = 0; i < 4; ++i)
      vreg[i] = *(const float4*)(vs_ + i * 4);
  };
  auto stage_commit = [&]() {
#pragma unroll
    for (int i = 0; i < 4; ++i) {
      int e = i * 2048 + tid * 4;
      int tl = e >> 12, key = (e >> 6) & 63, d0 = e & 63;
      s16x4 kb = { f2bf(kreg[i].x), f2bf(kreg[i].y), f2bf(kreg[i].z), f2bf(kreg[i].w) };
      *(s16x4*)&Kt[tl * TSZ + key * LSTR + d0] = kb;
    }
#pragma unroll
    for (int i = 0; i < 4; ++i) {
      Vt[vt * TSZ + (vd0 + i * 4 + 0) * LSTR + vkey] = f2bf(vreg[i].x);
      Vt[vt * TSZ + (vd0 + i * 4 + 1) * LSTR + vkey] = f2bf(vreg[i].y);
      Vt[vt * TSZ + (vd0 + i * 4 + 2) * LSTR + vkey] = f2bf(vreg[i].z);
      Vt[vt * TSZ + (vd0 + i * 4 + 3) * LSTR + vkey] = f2bf(vreg[i].w);
    }
  };

  // prologue: stage super-iter 0
  stage_issue(0);
  stage_commit();
  __syncthreads();

  for (int it = 0; it < nsup; ++it) {
    const bool more = (it + 1 < nsup);      // block-uniform
    if (more) stage_issue(2 * (it + 1));    // loads fly under compute

    const int myt = 2 * it + par;
    if (myt < ntiles) {                     // wave-uniform branch
      const short* kw = &Kt[par * TSZ];
      const short* vw = &Vt[par * TSZ];

      // ---- S = Q K^T (16 rows x 64 keys) ----
      f32x4 sc[4];
#pragma unroll
      for (int n = 0; n < 4; ++n) {
        f32x4 acc = vzero;
#pragma unroll
        for (int ks = 0; ks < 2; ++ks) {
          bf16x8 kf = __builtin_bit_cast(bf16x8,
              *(const s16x8*)&kw[(n * 16 + l16) * LSTR + ks * 32 + grp * 8]);
          acc = __builtin_amdgcn_mfma_f32_16x16x32_bf16(qf[ks], kf, acc, 0, 0, 0);
        }
        sc[n] = acc;
      }

      // ---- mask + online softmax (log2 domain) ----
      // C/D layout: col(key) = l16, row(q) = grp*4 + r
      float tmax[4] = {-1e30f, -1e30f, -1e30f, -1e30f};
#pragma unroll
      for (int n = 0; n < 4; ++n) {
        int keyg = myt * BK + n * 16 + l16;
        bool ok = keyg < len;
#pragma unroll
        for (int r = 0; r < 4; ++r) {
          float v = ok ? sc[n][r] : -1.0e6f;
          sc[n][r] = v;
          tmax[r] = fmaxf(tmax[r], v);
        }
      }
#pragma unroll
      for (int r = 0; r < 4; ++r) {
#pragma unroll
        for (int off = 1; off < 16; off <<= 1)
          tmax[r] = fmaxf(tmax[r], __shfl_xor(tmax[r], off));
      }
      float alpha[4];
#pragma unroll
      for (int r = 0; r < 4; ++r) {
        float mn = fmaxf(mrun[r], tmax[r]);
        alpha[r] = exp2f(mrun[r] - mn);
        mrun[r] = mn;
      }
      float p[4][4];
      float rs[4] = {0.f, 0.f, 0.f, 0.f};
#pragma unroll
      for (int n = 0; n < 4; ++n)
#pragma unroll
        for (int r = 0; r < 4; ++r) {
          float pv = exp2f(sc[n][r] - mrun[r]);
          p[n][r] = pv;
          rs[r] += pv;
        }
#pragma unroll
      for (int r = 0; r < 4; ++r) {
#pragma unroll
        for (int off = 1; off < 16; off <<= 1)
          rs[r] += __shfl_xor(rs[r], off);
        lrun[r] = lrun[r] * alpha[r] + rs[r];
      }
#pragma unroll
      for (int nd = 0; nd < 4; ++nd)
#pragma unroll
        for (int r = 0; r < 4; ++r)
          oacc[nd][r] *= alpha[r];

      // ---- P: C-layout -> bf16 A-layout, wave-local LDS round-trip ----
      short* pw = &Pt[wid * 16 * LSTR];
#pragma unroll
      for (int n = 0; n < 4; ++n)
#pragma unroll
        for (int r = 0; r < 4; ++r)
          pw[(grp * 4 + r) * LSTR + n * 16 + l16] = f2bf(p[n][r]);

      // wave-local RAW: drain this wave's LDS ops; fence scheduler (rule #18)
      asm volatile("s_waitcnt lgkmcnt(0)" ::: "memory");
      __builtin_amdgcn_sched_barrier(0);

      bf16x8 pf[2];
#pragma unroll
      for (int ks = 0; ks < 2; ++ks)
        pf[ks] = __builtin_bit_cast(bf16x8,
            *(const s16x8*)&pw[l16 * LSTR + ks * 32 + grp * 8]);

      // ---- O += P V ----
#pragma unroll
      for (int nd = 0; nd < 4; ++nd) {
#pragma unroll
        for (int ks = 0; ks < 2; ++ks) {
          bf16x8 vf = __builtin_bit_cast(bf16x8,
              *(const s16x8*)&vw[(nd * 16 + l16) * LSTR + ks * 32 + grp * 8]);
          oacc[nd] = __builtin_amdgcn_mfma_f32_16x16x32_bf16(pf[ks], vf, oacc[nd], 0, 0, 0);
        }
      }
    }

    __syncthreads();                       // all waves done reading Kt/Vt(it)
    if (more) {
      stage_commit();                      // write tiles for it+1
      __syncthreads();                     // LDS(it+1) ready
    }
  }

  // ---- combine wave pairs: odd wave publishes (O, m, l) via LDS ----
  float* CB = (float*)SM;   // 256 rows x 24 f32 = 24576 B, overlays Kt/Vt
  const int crow = qgrp * 64 + lane;
  if (par == 1) {
    float* dst = CB + (size_t)crow * 24;
#pragma unroll
    for (int nd = 0; nd < 4; ++nd) *(f32x4*)(dst + nd * 4) = oacc[nd];
    f32x4 mv = {mrun[0], mrun[1], mrun[2], mrun[3]};
    f32x4 lv = {lrun[0], lrun[1], lrun[2], lrun[3]};
    *(f32x4*)(dst + 16) = mv;
    *(f32x4*)(dst + 20) = lv;
  }
  __syncthreads();
  if (par == 0) {
    const float* src = CB + (size_t)crow * 24;
    f32x4 oo[4];
#pragma unroll
    for (int nd = 0; nd < 4; ++nd) oo[nd] = *(const f32x4*)(src + nd * 4);
    f32x4 mo = *(const f32x4*)(src + 16);
    f32x4 lo = *(const f32x4*)(src + 20);

    float ae[4], ao[4], inv[4];
#pragma unroll
    for (int r = 0; r < 4; ++r) {
      float m = fmaxf(mrun[r], mo[r]);
      ae[r] = exp2f(mrun[r] - m);
      ao[r] = exp2f(mo[r] - m);
      float l = lrun[r] * ae[r] + lo[r] * ao[r];
      inv[r] = 1.0f / l;
    }
    float* obase = Op + ((size_t)b * NQ + qb * BQ + qgrp * 16) * ND;
#pragma unroll
    for (int nd = 0; nd < 4; ++nd)
#pragma unroll
      for (int r = 0; r < 4; ++r)
        obase[(grp * 4 + r) * ND + nd * 16 + l16] =
            (oacc[nd][r] * ae[r] + oo[nd][r] * ao[r]) * inv[r];
  }
}

extern "C" void kernel_launch(void* const* d_in, const int* in_sizes, int n_in,
                              void* d_out, int out_size, void* d_ws, size_t ws_size,
                              hipStream_t stream) {
  const float* Qp = (const float*)d_in[0];
  const float* Kp = (const float*)d_in[1];
  const float* Vp = (const float*)d_in[2];
  const int*   VL = (const int*)d_in[3];
  float* Op = (float*)d_out;
  attn_fwd<<<dim3(NB * (NQ / BQ)), dim3(512), 0, stream>>>(Qp, Kp, Vp, VL, Op);
}